// Round 13
// baseline (45.320 us; speedup 1.0000x reference)
//
#include <hip/hip_runtime.h>

#define B 32
#define L 200
#define DIN 64
#define H 64
#define A 36

typedef __attribute__((ext_vector_type(8))) short short8;   // bf16 MFMA fragment
typedef __attribute__((ext_vector_type(4))) float floatx4;  // MFMA accumulator
typedef __attribute__((ext_vector_type(8))) float floatx8;

static __device__ __forceinline__ short f2bf(float f) {
    union { float f; unsigned u; } v; v.f = f;
    unsigned r = (v.u + 0x7FFF + ((v.u >> 16) & 1)) >> 16;  // RNE
    return (short)r;
}

// Kernel 1: h = x@ln_w + ln_b ; h f32, hb16 pre-swizzled bf16, cc = h@w1b.
// Block 0 also reorders w1a/w1c into MFMA-fragment order (f32).
__global__ __launch_bounds__(256) void prep_kernel(
    const float* __restrict__ x, const float* __restrict__ ln_w,
    const float* __restrict__ ln_b, const float* __restrict__ w1,
    float* __restrict__ h_out, float* __restrict__ cc_out, short* __restrict__ hb16_out,
    float* __restrict__ w1a_r, float* __restrict__ w1c_r)
{
    int wave = threadIdx.x >> 6;
    int lane = threadIdx.x & 63;
    int bl = __builtin_amdgcn_readfirstlane(blockIdx.x * 4 + wave);
    const float* xr = x + (size_t)bl * DIN;
    float p0 = ln_b[lane], p1 = 0.f;
    #pragma unroll
    for (int d = 0; d < DIN; d += 2) {
        p0 = fmaf(xr[d],     ln_w[d * H + lane],       p0);   // xr uniform -> s_load
        p1 = fmaf(xr[d + 1], ln_w[(d + 1) * H + lane], p1);
    }
    float acc = p0 + p1;
    __shared__ float hrow[4][H];
    hrow[wave][lane] = acc;
    h_out[(size_t)bl * H + lane] = acc;
    int j = bl % L;
    hb16_out[(size_t)bl * H + (lane ^ ((j & 7) << 3))] = f2bf(acc);   // swizzled
    if (lane < A) {
        float s0 = 0.f, s1 = 0.f;
        #pragma unroll
        for (int hh = 0; hh < H; hh += 2) {
            s0 = fmaf(hrow[wave][hh],     w1[(H + hh) * A + lane],     s0);   // w1b
            s1 = fmaf(hrow[wave][hh + 1], w1[(H + hh + 1) * A + lane], s1);
        }
        cc_out[(size_t)bl * A + lane] = s0 + s1;
    }
    if (blockIdx.x == 0) {
        // fragment-order tables: idx = ((s*3+n)*64 + lane)*8 + e
        for (int idx = threadIdx.x; idx < 2 * 3 * 64 * 8; idx += 256) {
            int e = idx & 7, ln = (idx >> 3) & 63, sn = idx >> 9;
            int s = sn / 3, n = sn - 3 * s;
            int k = s * 32 + (ln >> 4) * 8 + e;
            int c = n * 16 + (ln & 15);
            w1a_r[idx] = (c < A) ? w1[k * A + c] : 0.f;
            w1c_r[idx] = (c < A) ? w1[(2 * H + k) * A + c] : 0.f;
        }
    }
}

// Kernel 2: block=(b,bg'), bg reversed (longest first); wave w owns i = bg + 50w.
// TWO-PHASE staging: chunks 0-7 -> prologue -> barrier -> issue rest ->
// compute m<4 (overlapping flight) -> barrier -> compute m>=4.
__global__ __launch_bounds__(256) void score_kernel(
    const float* __restrict__ h, const short* __restrict__ hb16,
    const float* __restrict__ cc, const float* __restrict__ w1a_r,
    const float* __restrict__ w1c_r, const float* __restrict__ b1,
    const float* __restrict__ w2, const float* __restrict__ b2,
    float* __restrict__ out)
{
    int blk = blockIdx.x;
    int b  = blk / 50;
    int bg = 49 - (blk - b * 50);            // longest blocks dispatch first
    int wave = threadIdx.x >> 6;
    int lane = threadIdx.x & 63;
    int i = __builtin_amdgcn_readfirstlane(bg + 50 * wave);
    int l15 = lane & 15, l4 = lane >> 4;

    __shared__ __align__(16) short tile[208 * 64];  // pre-swizzled rows

    const short* hb16b = hb16 + (size_t)b * L * H;
    const float* h_b   = h + (size_t)b * L * H;

    // ---- phase-1 staging: chunks 0..7 (rows 0..63, m-tiles 0..3) ----
    int maxrow = bg + 150;                            // largest i in this block
    int nch = (((maxrow | 15) + 1) + 7) >> 3;         // 20..26 chunks of 8 rows
    for (int c = wave; c < 8; c += 4) {
        int j = c * 8 + (lane >> 3);
        const short* src = hb16b + (size_t)j * H + (lane & 7) * 8;
        __builtin_amdgcn_global_load_lds(
            (const __attribute__((address_space(1))) void*)src,
            (__attribute__((address_space(3))) void*)&tile[c * 512],
            16, 0, 0);
    }

    // ---- prologue (overlaps phase-1 flight) ----
    const float* hi = h_b + (size_t)i * H;            // uniform -> s_load
    float b2v = b2[0];
    // coalesced per-lane loads, then shfl redistribution (no scattered gathers)
    float ccl = (lane < A) ? (cc[((size_t)b * L + i) * A + lane] + b1[lane]) : 0.f;
    float w2l = (lane < A) ? w2[lane] : 0.f;
    float w2v[3][4], cbv[3][4];
    #pragma unroll
    for (int n = 0; n < 3; ++n) {
        #pragma unroll
        for (int r = 0; r < 4; ++r) {
            int a = n * 16 + l4 * 4 + r;
            cbv[n][r] = __shfl(ccl, a, 64);           // 0 for a>=A already
            w2v[n][r] = __shfl(w2l, a, 64);
        }
    }
    short8 afrag[2][3];                        // A-operand: B_i[a = n*16+l15][k]
    #pragma unroll
    for (int s = 0; s < 2; ++s) {
        float hik[8];
        #pragma unroll
        for (int e = 0; e < 8; ++e) hik[e] = hi[s * 32 + l4 * 8 + e];
        #pragma unroll
        for (int n = 0; n < 3; ++n) {
            floatx8 wa = *(const floatx8*)&w1a_r[(((s * 3 + n) * 64) + lane) * 8];
            floatx8 wc = *(const floatx8*)&w1c_r[(((s * 3 + n) * 64) + lane) * 8];
            #pragma unroll
            for (int e = 0; e < 8; ++e)
                afrag[s][n][e] = f2bf(fmaf(hik[e], wc[e], wa[e]));
        }
    }
    __syncthreads();                           // phase-1 rows ready

    // ---- issue phase-2 staging (flight hides under m=0..3 compute) ----
    for (int c = 8 + wave; c < nch; c += 4) {
        int j = c * 8 + (lane >> 3); if (j > L - 1) j = L - 1;
        const short* src = hb16b + (size_t)j * H + (lane & 7) * 8;
        __builtin_amdgcn_global_load_lds(
            (const __attribute__((address_space(1))) void*)src,
            (__attribute__((address_space(3))) void*)&tile[c * 512],
            16, 0, 0);
    }

    float oacc[4] = {0.f, 0.f, 0.f, 0.f};
    int mmax = (i >> 4) + 1;                   // wave-uniform
    int mlim1 = mmax < 4 ? mmax : 4;

    #pragma unroll 1
    for (int phase = 0; phase < 2; ++phase) {
        int m0   = phase ? 4 : 0;
        int mend = phase ? mmax : mlim1;
        for (int m = m0; m < mend; ++m) {
            int row = m * 16 + l15;
            const short* brow = tile + row * 64;
            int sw = (l15 & 7) << 3;
            short8 bf0 = *(const short8*)(brow + ((l4 * 8) ^ sw));
            short8 bf1 = *(const short8*)(brow + ((32 + l4 * 8) ^ sw));
            floatx4 c0 = {cbv[0][0], cbv[0][1], cbv[0][2], cbv[0][3]};
            floatx4 c1 = {cbv[1][0], cbv[1][1], cbv[1][2], cbv[1][3]};
            floatx4 c2 = {cbv[2][0], cbv[2][1], cbv[2][2], cbv[2][3]};
            c0 = __builtin_amdgcn_mfma_f32_16x16x32_bf16(afrag[0][0], bf0, c0, 0, 0, 0);
            c1 = __builtin_amdgcn_mfma_f32_16x16x32_bf16(afrag[0][1], bf0, c1, 0, 0, 0);
            c2 = __builtin_amdgcn_mfma_f32_16x16x32_bf16(afrag[0][2], bf0, c2, 0, 0, 0);
            c0 = __builtin_amdgcn_mfma_f32_16x16x32_bf16(afrag[1][0], bf1, c0, 0, 0, 0);
            c1 = __builtin_amdgcn_mfma_f32_16x16x32_bf16(afrag[1][1], bf1, c1, 0, 0, 0);
            c2 = __builtin_amdgcn_mfma_f32_16x16x32_bf16(afrag[1][2], bf1, c2, 0, 0, 0);
            // epilogue: leaky = max(x, 0.01x); 3 indep chains; 2 shfl rounds
            float sp0 = 0.f, sp1 = 0.f, sp2 = 0.f;
            #pragma unroll
            for (int r = 0; r < 4; ++r) {
                sp0 = fmaf(fmaxf(c0[r], 0.01f * c0[r]), w2v[0][r], sp0);
                sp1 = fmaf(fmaxf(c1[r], 0.01f * c1[r]), w2v[1][r], sp1);
                sp2 = fmaf(fmaxf(c2[r], 0.01f * c2[r]), w2v[2][r], sp2);
            }
            float sp = (sp0 + sp1) + sp2;
            sp += __shfl_xor(sp, 16, 64);
            sp += __shfl_xor(sp, 32, 64);      // all lanes: score[j = m*16+l15]
            float sc = (row <= i) ? sp + b2v : 0.f;

            // PV: coalesced f32 global reads; score broadcast via readlane (SGPR)
            const float* hjb = h_b + (size_t)(m * 16) * H + lane;
            #pragma unroll
            for (int rb = 0; rb < 4; ++rb) {
                #pragma unroll
                for (int q = 0; q < 4; ++q) {
                    int jq = rb * 4 + q;
                    float sq = __int_as_float(
                        __builtin_amdgcn_readlane(__float_as_int(sc), jq));
                    float hv = hjb[jq * H];    // dword, imm offset, L1/L2-hot
                    oacc[rb] = fmaf(sq, hv, oacc[rb]);
                }
            }
        }
        if (phase == 0) __syncthreads();       // phase-2 rows ready
    }

    out[((size_t)b * L + i) * H + lane] = (oacc[0] + oacc[1]) + (oacc[2] + oacc[3]);
}

extern "C" void kernel_launch(void* const* d_in, const int* in_sizes, int n_in,
                              void* d_out, int out_size, void* d_ws, size_t ws_size,
                              hipStream_t stream) {
    const float* x    = (const float*)d_in[0];
    const float* ln_w = (const float*)d_in[1];
    const float* ln_b = (const float*)d_in[2];
    const float* w1   = (const float*)d_in[3];
    const float* b1   = (const float*)d_in[4];
    const float* w2   = (const float*)d_in[5];
    const float* b2   = (const float*)d_in[6];
    float* out = (float*)d_out;

    float* h_ws   = (float*)d_ws;                             // B*L*H f32
    float* cc_ws  = h_ws + (size_t)B * L * H;                 // B*L*A f32
    short* hb16_ws = (short*)(cc_ws + (size_t)B * L * A);     // B*L*H bf16 (swizzled)
    float* w1a_r  = (float*)(hb16_ws + (size_t)B * L * H);    // 3072 f32
    float* w1c_r  = w1a_r + 3072;                             // 3072 f32

    prep_kernel<<<(B * L) / 4, 256, 0, stream>>>(x, ln_w, ln_b, w1, h_ws, cc_ws,
                                                 hb16_ws, w1a_r, w1c_r);
    score_kernel<<<B * 50, 256, 0, stream>>>(h_ws, hb16_ws, cc_ws, w1a_r, w1c_r,
                                             b1, w2, b2, out);
}

// Round 14
// 38.280 us; speedup vs baseline: 1.1839x; 1.1839x over previous
//
#include <hip/hip_runtime.h>

#define B 32
#define L 200
#define DIN 64
#define H 64
#define A 36

typedef __attribute__((ext_vector_type(8))) short short8;   // bf16 MFMA fragment
typedef __attribute__((ext_vector_type(4))) float floatx4;  // MFMA accumulator
typedef __attribute__((ext_vector_type(8))) float floatx8;

static __device__ __forceinline__ short f2bf(float f) {
    union { float f; unsigned u; } v; v.f = f;
    unsigned r = (v.u + 0x7FFF + ((v.u >> 16) & 1)) >> 16;  // RNE
    return (short)r;
}

// Kernel 1: h = x@ln_w + ln_b ; h f32, hb16 pre-swizzled bf16, cc = h@w1b.
// Block 0 also reorders w1a/w1c into MFMA-fragment order (f32).
__global__ __launch_bounds__(256) void prep_kernel(
    const float* __restrict__ x, const float* __restrict__ ln_w,
    const float* __restrict__ ln_b, const float* __restrict__ w1,
    float* __restrict__ h_out, float* __restrict__ cc_out, short* __restrict__ hb16_out,
    float* __restrict__ w1a_r, float* __restrict__ w1c_r)
{
    int wave = threadIdx.x >> 6;
    int lane = threadIdx.x & 63;
    int bl = __builtin_amdgcn_readfirstlane(blockIdx.x * 4 + wave);
    const float* xr = x + (size_t)bl * DIN;
    float p0 = ln_b[lane], p1 = 0.f;
    #pragma unroll
    for (int d = 0; d < DIN; d += 2) {
        p0 = fmaf(xr[d],     ln_w[d * H + lane],       p0);   // xr uniform -> s_load
        p1 = fmaf(xr[d + 1], ln_w[(d + 1) * H + lane], p1);
    }
    float acc = p0 + p1;
    __shared__ float hrow[4][H];
    hrow[wave][lane] = acc;
    h_out[(size_t)bl * H + lane] = acc;
    int j = bl % L;
    hb16_out[(size_t)bl * H + (lane ^ ((j & 7) << 3))] = f2bf(acc);   // swizzled
    if (lane < A) {
        float s0 = 0.f, s1 = 0.f;
        #pragma unroll
        for (int hh = 0; hh < H; hh += 2) {
            s0 = fmaf(hrow[wave][hh],     w1[(H + hh) * A + lane],     s0);   // w1b
            s1 = fmaf(hrow[wave][hh + 1], w1[(H + hh + 1) * A + lane], s1);
        }
        cc_out[(size_t)bl * A + lane] = s0 + s1;
    }
    if (blockIdx.x == 0) {
        // fragment-order tables: idx = ((s*3+n)*64 + lane)*8 + e
        for (int idx = threadIdx.x; idx < 2 * 3 * 64 * 8; idx += 256) {
            int e = idx & 7, ln = (idx >> 3) & 63, sn = idx >> 9;
            int s = sn / 3, n = sn - 3 * s;
            int k = s * 32 + (ln >> 4) * 8 + e;
            int c = n * 16 + (ln & 15);
            w1a_r[idx] = (c < A) ? w1[k * A + c] : 0.f;
            w1c_r[idx] = (c < A) ? w1[(2 * H + k) * A + c] : 0.f;
        }
    }
}

// Kernel 2: block=(b,g), g reversed (longest first); wave w owns i = 4g+w.
// Intra-block balanced (waves differ by <=1 m-iter -> block retires as a unit).
// Blocks stage only rows 0..4g+3 (2..26 chunks). Single barrier.
// m-loop: explicit software pipeline of the B-fragment ds_read_b128 pair.
__global__ __launch_bounds__(256) void score_kernel(
    const float* __restrict__ h, const short* __restrict__ hb16,
    const float* __restrict__ cc, const float* __restrict__ w1a_r,
    const float* __restrict__ w1c_r, const float* __restrict__ b1,
    const float* __restrict__ w2, const float* __restrict__ b2,
    float* __restrict__ out)
{
    int blk = blockIdx.x;
    int b  = blk / 50;
    int g  = 49 - (blk - b * 50);            // longest blocks dispatch first
    int wave = threadIdx.x >> 6;
    int lane = threadIdx.x & 63;
    int i = __builtin_amdgcn_readfirstlane(4 * g + wave);     // 0..199
    int l15 = lane & 15, l4 = lane >> 4;

    __shared__ __align__(16) short tile[208 * 64];  // pre-swizzled rows

    const short* hb16b = hb16 + (size_t)b * L * H;
    const float* h_b   = h + (size_t)b * L * H;

    // ---- stage rows 0 .. (4g+3 | 15): 2..26 chunks of 8 rows ----
    int maxrow = 4 * g + 3;
    int nch = (((maxrow | 15) + 1) + 7) >> 3;
    for (int c = wave; c < nch; c += 4) {
        int j = c * 8 + (lane >> 3); if (j > L - 1) j = L - 1;
        const short* src = hb16b + (size_t)j * H + (lane & 7) * 8;
        __builtin_amdgcn_global_load_lds(
            (const __attribute__((address_space(1))) void*)src,
            (__attribute__((address_space(3))) void*)&tile[c * 512],
            16, 0, 0);
    }

    // ---- prologue (overlaps staging flight) ----
    const float* hi = h_b + (size_t)i * H;            // uniform -> s_load
    float b2v = b2[0];
    // coalesced per-lane loads + shfl redistribution (no scattered gathers)
    float ccl = (lane < A) ? (cc[((size_t)b * L + i) * A + lane] + b1[lane]) : 0.f;
    float w2l = (lane < A) ? w2[lane] : 0.f;
    float w2v[3][4], cbv[3][4];
    #pragma unroll
    for (int n = 0; n < 3; ++n) {
        #pragma unroll
        for (int r = 0; r < 4; ++r) {
            int a = n * 16 + l4 * 4 + r;
            cbv[n][r] = __shfl(ccl, a, 64);           // 0 for a>=A already
            w2v[n][r] = __shfl(w2l, a, 64);
        }
    }
    short8 afrag[2][3];                        // A-operand: B_i[a = n*16+l15][k]
    #pragma unroll
    for (int s = 0; s < 2; ++s) {
        float hik[8];
        #pragma unroll
        for (int e = 0; e < 8; ++e) hik[e] = hi[s * 32 + l4 * 8 + e];
        #pragma unroll
        for (int n = 0; n < 3; ++n) {
            floatx8 wa = *(const floatx8*)&w1a_r[(((s * 3 + n) * 64) + lane) * 8];
            floatx8 wc = *(const floatx8*)&w1c_r[(((s * 3 + n) * 64) + lane) * 8];
            #pragma unroll
            for (int e = 0; e < 8; ++e)
                afrag[s][n][e] = f2bf(fmaf(hik[e], wc[e], wa[e]));
        }
    }
    __syncthreads();                           // staging complete

    float oacc[4] = {0.f, 0.f, 0.f, 0.f};
    int mmax = (i >> 4) + 1;                   // wave-uniform
    int sw = (l15 & 7) << 3;

    // software pipeline: preload m=0 B-fragments
    const short* brow0 = tile + l15 * 64;
    short8 bfc0 = *(const short8*)(brow0 + ((l4 * 8) ^ sw));
    short8 bfc1 = *(const short8*)(brow0 + ((32 + l4 * 8) ^ sw));

    for (int m = 0; m < mmax; ++m) {
        // prefetch next iteration's fragments (hides ds_read under MFMA+VALU)
        short8 bfn0, bfn1;
        if (m + 1 < mmax) {
            const short* brown = tile + ((m + 1) * 16 + l15) * 64;
            bfn0 = *(const short8*)(brown + ((l4 * 8) ^ sw));
            bfn1 = *(const short8*)(brown + ((32 + l4 * 8) ^ sw));
        }
        int row = m * 16 + l15;
        floatx4 c0 = {cbv[0][0], cbv[0][1], cbv[0][2], cbv[0][3]};
        floatx4 c1 = {cbv[1][0], cbv[1][1], cbv[1][2], cbv[1][3]};
        floatx4 c2 = {cbv[2][0], cbv[2][1], cbv[2][2], cbv[2][3]};
        c0 = __builtin_amdgcn_mfma_f32_16x16x32_bf16(afrag[0][0], bfc0, c0, 0, 0, 0);
        c1 = __builtin_amdgcn_mfma_f32_16x16x32_bf16(afrag[0][1], bfc0, c1, 0, 0, 0);
        c2 = __builtin_amdgcn_mfma_f32_16x16x32_bf16(afrag[0][2], bfc0, c2, 0, 0, 0);
        c0 = __builtin_amdgcn_mfma_f32_16x16x32_bf16(afrag[1][0], bfc1, c0, 0, 0, 0);
        c1 = __builtin_amdgcn_mfma_f32_16x16x32_bf16(afrag[1][1], bfc1, c1, 0, 0, 0);
        c2 = __builtin_amdgcn_mfma_f32_16x16x32_bf16(afrag[1][2], bfc1, c2, 0, 0, 0);
        // epilogue: leaky = max(x, 0.01x); 3 indep chains; 2 shfl rounds
        float sp0 = 0.f, sp1 = 0.f, sp2 = 0.f;
        #pragma unroll
        for (int r = 0; r < 4; ++r) {
            sp0 = fmaf(fmaxf(c0[r], 0.01f * c0[r]), w2v[0][r], sp0);
            sp1 = fmaf(fmaxf(c1[r], 0.01f * c1[r]), w2v[1][r], sp1);
            sp2 = fmaf(fmaxf(c2[r], 0.01f * c2[r]), w2v[2][r], sp2);
        }
        float sp = (sp0 + sp1) + sp2;
        sp += __shfl_xor(sp, 16, 64);
        sp += __shfl_xor(sp, 32, 64);          // all lanes: score[j = m*16+l15]
        float sc = (row <= i) ? sp + b2v : 0.f;

        // PV: coalesced f32 global reads; score broadcast via readlane (SGPR)
        const float* hjb = h_b + (size_t)(m * 16) * H + lane;
        #pragma unroll
        for (int rb = 0; rb < 4; ++rb) {
            #pragma unroll
            for (int q = 0; q < 4; ++q) {
                int jq = rb * 4 + q;
                float sq = __int_as_float(
                    __builtin_amdgcn_readlane(__float_as_int(sc), jq));
                float hv = hjb[jq * H];        // dword, imm offset, L1/L2-hot
                oacc[rb] = fmaf(sq, hv, oacc[rb]);
            }
        }
        bfc0 = bfn0;
        bfc1 = bfn1;
    }

    out[((size_t)b * L + i) * H + lane] = (oacc[0] + oacc[1]) + (oacc[2] + oacc[3]);
}

extern "C" void kernel_launch(void* const* d_in, const int* in_sizes, int n_in,
                              void* d_out, int out_size, void* d_ws, size_t ws_size,
                              hipStream_t stream) {
    const float* x    = (const float*)d_in[0];
    const float* ln_w = (const float*)d_in[1];
    const float* ln_b = (const float*)d_in[2];
    const float* w1   = (const float*)d_in[3];
    const float* b1   = (const float*)d_in[4];
    const float* w2   = (const float*)d_in[5];
    const float* b2   = (const float*)d_in[6];
    float* out = (float*)d_out;

    float* h_ws   = (float*)d_ws;                             // B*L*H f32
    float* cc_ws  = h_ws + (size_t)B * L * H;                 // B*L*A f32
    short* hb16_ws = (short*)(cc_ws + (size_t)B * L * A);     // B*L*H bf16 (swizzled)
    float* w1a_r  = (float*)(hb16_ws + (size_t)B * L * H);    // 3072 f32
    float* w1c_r  = w1a_r + 3072;                             // 3072 f32

    prep_kernel<<<(B * L) / 4, 256, 0, stream>>>(x, ln_w, ln_b, w1, h_ws, cc_ws,
                                                 hb16_ws, w1a_r, w1c_r);
    score_kernel<<<B * 50, 256, 0, stream>>>(h_ws, hb16_ws, cc_ws, w1a_r, w1c_r,
                                             b1, w2, b2, out);
}